// Round 4
// baseline (181.588 us; speedup 1.0000x reference)
//
#include <hip/hip_runtime.h>
#include <hip/hip_bf16.h>

// Fused MHA fwd: out = softmax(scale*Q@K^T + bias) @ V
// B=2 H=16 S=2048 D=64, fp32 in/out, bf16 MFMA.
// R3 (best, 84.5us): XOR-swizzled LDS, 16x16 MFMA, 4x16q waves, P via LDS.
// R5/R6: 32q waves + in-reg P -> VALU down but occupancy halved (2048 waves)
//   and the 32x32 read geometry cost 4 conflict-cyc/ds_read_b128 (4.2M).
// R7: R3 structure EXACTLY (16q waves, 4096 waves, zero-conflict 16x16 reads,
//   single-buffer staging) + swapped QK^T (mfma(K,Q)) so q = C-col = l15 is
//   lane-local. P stays in registers: 8 cvt_pk + 4x{pl32swap,pl16swap} build
//   the PV A-fragment. Deletes per wave-tile: 16 ds_write_b16, 2 P ds_reads,
//   48-op f2b chain, P lgkm round-trip, 8KB LDS. Bias: 4 f32x4 loads (kv now
//   contiguous per lane) instead of 16 scalar.

#define SEQ 2048
#define DH  64
#define BHN 32
#define NTILE (SEQ / 64)
#define LOG2E 1.44269504088896f

typedef __attribute__((ext_vector_type(8))) short bf16x8;
typedef __attribute__((ext_vector_type(4))) float f32x4;
typedef __attribute__((ext_vector_type(8))) short short8v;

__device__ inline short f2b(float x) {
    union { float f; unsigned u; } v; v.f = x;
    unsigned r = v.u + 0x7fff + ((v.u >> 16) & 1);
    return (short)(r >> 16);
}

__device__ inline unsigned cvt_pk(float lo, float hi) {
    unsigned r;
    asm("v_cvt_pk_bf16_f32 %0, %1, %2" : "=v"(r) : "v"(lo), "v"(hi));
    return r;
}

// v_permlane32_swap_b32 x,y: x.{r2,r3} <-> y.{r0,r1} (16-lane rows r0..r3).
// After: x = {x.r0, x.r1, y.r0, y.r1}, y = {x.r2, x.r3, y.r2, y.r3}.
__device__ inline void pl32swap(unsigned& x, unsigned& y) {
    asm("v_permlane32_swap_b32 %0, %1" : "+v"(x), "+v"(y));
}
// v_permlane16_swap_b32 x,y: x.{r1,r3} <-> y.{r0,r2}.
// After: x = {x.r0, y.r0, x.r2, y.r2}, y = {x.r1, y.r1, x.r3, y.r3}.
__device__ inline void pl16swap(unsigned& x, unsigned& y) {
    asm("v_permlane16_swap_b32 %0, %1" : "+v"(x), "+v"(y));
}

__device__ inline void gl_lds16(const void* g, void* l) {
    __builtin_amdgcn_global_load_lds(
        (const __attribute__((address_space(1))) void*)g,
        (__attribute__((address_space(3))) void*)l, 16, 0, 0);
}

// ---- fused prep: K fp32->bf16 (same layout) + V fp32->bf16 transposed ----
__global__ __launch_bounds__(256)
void prep_kv(const float* __restrict__ K, const float* __restrict__ V,
             short* __restrict__ Kb, short* __restrict__ Vt) {
    __shared__ short t[64 * 72];
    const int tid = threadIdx.x;
    const int bh = blockIdx.x >> 5, st = blockIdx.x & 31, s0 = st * 64;

    {
        const float* Kp = K + ((size_t)bh * SEQ + s0) * DH;
        short* Ko = Kb + ((size_t)bh * SEQ + s0) * DH;
        #pragma unroll
        for (int i = 0; i < 2; ++i) {
            size_t o = (size_t)(tid + i * 256) * 8;
            f32x4 a = *(const f32x4*)(Kp + o);
            f32x4 b = *(const f32x4*)(Kp + o + 4);
            short8v s;
            #pragma unroll
            for (int j = 0; j < 4; ++j) { s[j] = f2b(a[j]); s[4 + j] = f2b(b[j]); }
            *(short8v*)(Ko + o) = s;
        }
    }

    const float* Vb = V + (size_t)bh * SEQ * DH + (size_t)s0 * DH;
    #pragma unroll
    for (int i = 0; i < 4; ++i) {
        int c = tid + i * 256, s = c >> 4, c4 = c & 15;
        f32x4 v = *(const f32x4*)(Vb + s * DH + c4 * 4);
        #pragma unroll
        for (int j = 0; j < 4; ++j) t[s * 72 + c4 * 4 + j] = f2b(v[j]);
    }
    __syncthreads();
    const int d = tid >> 2, part = tid & 3;
    short8v lo, hi;
    #pragma unroll
    for (int j = 0; j < 8; ++j) {
        lo[j] = t[(part * 16 + j) * 72 + d];
        hi[j] = t[(part * 16 + 8 + j) * 72 + d];
    }
    short* outp = Vt + (size_t)bh * DH * SEQ + (size_t)d * SEQ + s0 + part * 16;
    *(short8v*)outp = lo;
    *(short8v*)(outp + 8) = hi;
}

// ---- main fused attention ----
// 16x16x32 fragment facts (verified by R3 passing):
//   A: m=l15, k=l4*8+j.  B: n=l15, k=l4*8+j.  C/D: col=l15(n), row=l4*4+reg(m).
// Swapped QK (A=K, B=Q): sacc[nt] reg r = S^T[kv = nt*16 + l4*4 + r][q = l15].
// PV A-frag needs m=q=l15, k(kv in 32-block) = l4*8+j. Own pk-words per
// subtile nt: pair0 = rows l4*4+{0,1}, pair1 = rows l4*4+{2,3}.
// For ks-half (subtiles X=2ks, Y=2ks+1), with A=Xp0,B=Xp1,C=Yp0,D=Yp1:
//   pl32swap(A,C); pl16swap(A,C) -> A = {A.r0,A.r2,C.r0,C.r2} = W0, C = W2
//   pl32swap(B,D); pl16swap(B,D) -> B = W1, D = W3
// Check (dest 16-lane group t): W0@t0 = Xp0@r0 = rows{0,1} (k=l4*8+{0,1}, l4=0) OK
//   W0@t1 = Xp0@r2 = rows{8,9} OK; W0@t2 = Yp0@r0 = rows{16,17} OK;
//   W2@t0 = Xp0@r1 = rows{4,5} (k {4,5}) OK; W3@t0 = Xp1@r1 = rows{6,7} OK.
__global__ __launch_bounds__(256, 4)
void mha_main(const float* __restrict__ Q, const float* __restrict__ Bias,
              const short* __restrict__ Kb, const short* __restrict__ Vt,
              float* __restrict__ Out)
{
    __shared__ short lds_k[64 * DH];      // K tile [kv][d], swizzled
    __shared__ short lds_v[64 * DH];      // Vt tile [d][kv], swizzled

    const int tid = threadIdx.x, lane = tid & 63, wave = tid >> 6;
    const int l15 = lane & 15, l4 = lane >> 4;
    const int qb = blockIdx.x & 31, bh = blockIdx.x >> 5;
    const int q0 = qb * 64;
    const int qw = q0 + wave * 16;        // this wave's q base

    const float* Qb = Q + (size_t)bh * SEQ * DH;
    const short* Kh = Kb + (size_t)bh * SEQ * DH;
    const short* Vh = Vt + (size_t)bh * DH * SEQ;
    float* Ob = Out + (size_t)bh * SEQ * DH;

    // Q B-frags (n=l15 -> q=qw+l15, k=ks*32+l4*8+j), pre-scaled by LOG2E/8
    bf16x8 qf[2];
    {
        const float* qp = Qb + (size_t)(qw + l15) * DH;
        const float qs = 0.125f * LOG2E;
        #pragma unroll
        for (int ks = 0; ks < 2; ++ks) {
            short tmp[8];
            #pragma unroll
            for (int j = 0; j < 8; ++j) tmp[j] = f2b(qp[ks * 32 + l4 * 8 + j] * qs);
            qf[ks] = *reinterpret_cast<bf16x8*>(tmp);
        }
    }

    f32x4 o_acc[4];
    #pragma unroll
    for (int dt = 0; dt < 4; ++dt) o_acc[dt] = f32x4{0.f, 0.f, 0.f, 0.f};
    float l_acc = 0.f;                    // partial denom for q = l15

    // staging (R3-identical): physical chunk c_ of row r_ gets global chunk
    // c_^(r_&7); reads use (logical ^ (row&7)).
    const short* kg[2]; const short* vg[2]; short* kl[2]; short* vl[2];
    #pragma unroll
    for (int p = 0; p < 2; ++p) {
        int slot = p * 256 + wave * 64 + lane;   // 0..511
        int r_ = slot >> 3;                      // row 0..63
        int c_ = slot & 7;                       // physical 16B chunk
        int cg = c_ ^ (r_ & 7);                  // global chunk to fetch
        kg[p] = Kh + (size_t)r_ * DH + cg * 8;
        vg[p] = Vh + (size_t)r_ * SEQ + cg * 8;
        kl[p] = &lds_k[(size_t)(p * 256 + wave * 64) * 8];
        vl[p] = &lds_v[(size_t)(p * 256 + wave * 64) * 8];
    }
    // bias: lane needs rows kv = k0+nt*16+l4*4+{0..3} at col q = qw+l15
    // -> contiguous f32x4 per nt.
    const float* bp0 = Bias + (size_t)(qw + l15) * SEQ + l4 * 4;
    const int swz = l15 & 7;                     // read-side XOR

    for (int kt = 0; kt < NTILE; ++kt) {
        const int k0 = kt * 64;
        __syncthreads();                          // prior tile reads done
        gl_lds16(kg[0] + (size_t)k0 * DH, kl[0]);
        gl_lds16(kg[1] + (size_t)k0 * DH, kl[1]);
        gl_lds16(vg[0] + k0, vl[0]);
        gl_lds16(vg[1] + k0, vl[1]);

        // bias -> C init: sacc[nt] reg r = LOG2E * bias[qw+l15][k0+nt*16+l4*4+r]
        f32x4 sacc[4];
        const float* bp = bp0 + k0;
        #pragma unroll
        for (int nt = 0; nt < 4; ++nt) {
            f32x4 b = *(const f32x4*)(bp + nt * 16);
            #pragma unroll
            for (int r = 0; r < 4; ++r) sacc[nt][r] = b[r] * LOG2E;
        }

        __syncthreads();                          // staging complete

        // QK^T swapped: A=K subtile nt (m=kv), B=Q (n=q)
        #pragma unroll
        for (int ks = 0; ks < 2; ++ks)
            #pragma unroll
            for (int nt = 0; nt < 4; ++nt) {
                int cc = (ks * 4 + l4) ^ swz;
                bf16x8 kf = *(const bf16x8*)&lds_k[(nt * 16 + l15) * DH + cc * 8];
                sacc[nt] = __builtin_amdgcn_mfma_f32_16x16x32_bf16(kf, qf[ks], sacc[nt], 0, 0, 0);
            }

        // softmax (max-free), fully in registers
        unsigned pkw[4][2];                       // [nt][pair]
        #pragma unroll
        for (int nt = 0; nt < 4; ++nt) {
            float p0 = __builtin_amdgcn_exp2f(sacc[nt][0]);
            float p1 = __builtin_amdgcn_exp2f(sacc[nt][1]);
            float p2 = __builtin_amdgcn_exp2f(sacc[nt][2]);
            float p3 = __builtin_amdgcn_exp2f(sacc[nt][3]);
            l_acc += (p0 + p1) + (p2 + p3);
            pkw[nt][0] = cvt_pk(p0, p1);
            pkw[nt][1] = cvt_pk(p2, p3);
        }

        // O += P @ V ; A-frag built by permlane routing (see header comment)
        #pragma unroll
        for (int ks = 0; ks < 2; ++ks) {
            unsigned A = pkw[2 * ks][0], B = pkw[2 * ks][1];
            unsigned C = pkw[2 * ks + 1][0], D = pkw[2 * ks + 1][1];
            pl32swap(A, C); pl16swap(A, C);       // A=W0, C=W2
            pl32swap(B, D); pl16swap(B, D);       // B=W1, D=W3
            union { unsigned w[4]; bf16x8 v; } u;
            u.w[0] = A; u.w[1] = B; u.w[2] = C; u.w[3] = D;
            bf16x8 pf = u.v;

            int cc = (ks * 4 + l4) ^ swz;
            #pragma unroll
            for (int dt = 0; dt < 4; ++dt) {
                bf16x8 vf = *(const bf16x8*)&lds_v[(dt * 16 + l15) * DH + cc * 8];
                o_acc[dt] = __builtin_amdgcn_mfma_f32_16x16x32_bf16(pf, vf, o_acc[dt], 0, 0, 0);
            }
        }
    }

    // denom: reduce over the 4 lane-groups sharing l15
    l_acc += __shfl_xor(l_acc, 16, 64);
    l_acc += __shfl_xor(l_acc, 32, 64);
    float linv = 1.0f / l_acc;                    // for q = l15

    // O-write: o_acc[dt] reg r -> row q = qw + l4*4 + r, col dv = dt*16 + l15
    #pragma unroll
    for (int r = 0; r < 4; ++r) {
        float inv = __shfl(linv, l4 * 4 + r, 64);
        float* op = Ob + (size_t)(qw + l4 * 4 + r) * DH + l15;
        #pragma unroll
        for (int dt = 0; dt < 4; ++dt) op[dt * 16] = o_acc[dt][r] * inv;
    }
}

extern "C" void kernel_launch(void* const* d_in, const int* in_sizes, int n_in,
                              void* d_out, int out_size, void* d_ws, size_t ws_size,
                              hipStream_t stream) {
    const float* Q    = (const float*)d_in[0];
    const float* K    = (const float*)d_in[1];
    const float* V    = (const float*)d_in[2];
    const float* Bias = (const float*)d_in[3];
    float* O          = (float*)d_out;

    short* Kb = (short*)d_ws;                    // 8 MB
    short* Vt = Kb + (size_t)BHN * SEQ * DH;     // 8 MB

    prep_kv<<<dim3(BHN * 32), dim3(256), 0, stream>>>(K, V, Kb, Vt);
    mha_main<<<dim3(BHN * 32), dim3(256), 0, stream>>>(Q, Bias, Kb, Vt, O);
}

// Round 5
// 172.093 us; speedup vs baseline: 1.0552x; 1.0552x over previous
//
#include <hip/hip_runtime.h>
#include <hip/hip_bf16.h>

// Fused MHA fwd: out = softmax(scale*Q@K^T + bias) @ V
// B=2 H=16 S=2048 D=64, fp32 in/out, bf16 MFMA.
// R3 (84.5us): XOR-swizzled LDS, 16x16 MFMA, 4x16q waves, P via per-wave LDS.
// R4-R7: dbuf / 32q in-reg-P / 16q in-reg-P all regressed -> the inner tile
//   shape of R3 is the local optimum; the cost is barrier-drain frequency and
//   staging locality, not VALU work.
// R8: R3 inner tile EXACTLY, but (a) KVBLK=128: one barrier pair per 128 kv
//   (two 64-kv halves computed back-to-back, no barrier between; per-wave P
//   buffer reuse is wave-ordered, same guarantee R3 uses across tiles);
//   8 outstanding global_load_lds per stage. LDS 24->40KB keeps 4 blocks/CU.
//   (b) XCD swizzle (bijective, 1024%8==0): all 32 q-blocks of a bh on one
//   XCD -> its 512KB Kb/Vt stays in that XCD's L2, shortening every drain.

#define SEQ 2048
#define DH  64
#define BHN 32
#define KV  128
#define NTILE (SEQ / KV)
#define LOG2E 1.44269504088896f

typedef __attribute__((ext_vector_type(8))) short bf16x8;
typedef __attribute__((ext_vector_type(4))) float f32x4;
typedef __attribute__((ext_vector_type(8))) short short8v;

__device__ inline short f2b(float x) {
    union { float f; unsigned u; } v; v.f = x;
    unsigned r = v.u + 0x7fff + ((v.u >> 16) & 1);
    return (short)(r >> 16);
}

__device__ inline void gl_lds16(const void* g, void* l) {
    __builtin_amdgcn_global_load_lds(
        (const __attribute__((address_space(1))) void*)g,
        (__attribute__((address_space(3))) void*)l, 16, 0, 0);
}

// ---- fused prep: K fp32->bf16 (same layout) + V fp32->bf16 transposed ----
__global__ __launch_bounds__(256)
void prep_kv(const float* __restrict__ K, const float* __restrict__ V,
             short* __restrict__ Kb, short* __restrict__ Vt) {
    __shared__ short t[64 * 72];
    const int tid = threadIdx.x;
    const int bh = blockIdx.x >> 5, st = blockIdx.x & 31, s0 = st * 64;

    {
        const float* Kp = K + ((size_t)bh * SEQ + s0) * DH;
        short* Ko = Kb + ((size_t)bh * SEQ + s0) * DH;
        #pragma unroll
        for (int i = 0; i < 2; ++i) {
            size_t o = (size_t)(tid + i * 256) * 8;
            f32x4 a = *(const f32x4*)(Kp + o);
            f32x4 b = *(const f32x4*)(Kp + o + 4);
            short8v s;
            #pragma unroll
            for (int j = 0; j < 4; ++j) { s[j] = f2b(a[j]); s[4 + j] = f2b(b[j]); }
            *(short8v*)(Ko + o) = s;
        }
    }

    const float* Vb = V + (size_t)bh * SEQ * DH + (size_t)s0 * DH;
    #pragma unroll
    for (int i = 0; i < 4; ++i) {
        int c = tid + i * 256, s = c >> 4, c4 = c & 15;
        f32x4 v = *(const f32x4*)(Vb + s * DH + c4 * 4);
        #pragma unroll
        for (int j = 0; j < 4; ++j) t[s * 72 + c4 * 4 + j] = f2b(v[j]);
    }
    __syncthreads();
    const int d = tid >> 2, part = tid & 3;
    short8v lo, hi;
    #pragma unroll
    for (int j = 0; j < 8; ++j) {
        lo[j] = t[(part * 16 + j) * 72 + d];
        hi[j] = t[(part * 16 + 8 + j) * 72 + d];
    }
    short* outp = Vt + (size_t)bh * DH * SEQ + (size_t)d * SEQ + s0 + part * 16;
    *(short8v*)outp = lo;
    *(short8v*)(outp + 8) = hi;
}

// ---- main fused attention ----
// LDS swizzle: logical 8-short chunk c of row r lives at physical c^(r&7)
// (XOR on low 3 chunk bits only; V rows have 16 chunks, bit 3 untouched).
// Staging fetches global chunk c^(r&7) into physical chunk c; reads XOR back.
// All ds_read_b128 patterns <=2-way (R3-verified: conflicts == 0).
__global__ __launch_bounds__(256, 4)
void mha_main(const float* __restrict__ Q, const float* __restrict__ Bias,
              const short* __restrict__ Kb, const short* __restrict__ Vt,
              float* __restrict__ Out)
{
    __shared__ short lds_k[KV * DH];      // K tile [kv=128][d=64], swizzled, 16KB
    __shared__ short lds_v[DH * KV];      // Vt tile [d=64][kv=128], swizzled, 16KB
    __shared__ short lds_p[4 * 16 * 64];  // per-wave P [m][n], swizzled, 8KB

    const int tid = threadIdx.x, lane = tid & 63, wave = tid >> 6;
    const int l15 = lane & 15, l4 = lane >> 4;

    // XCD swizzle: blocks bid%8==x run on XCD x; give each XCD a contiguous
    // logical range (4 full bh, each with all 32 q-blocks -> K/V L2-resident).
    const int bid = blockIdx.x;
    const int swzb = (bid & 7) * (BHN * 32 / 8) + (bid >> 3);
    const int qb = swzb & 31, bh = swzb >> 5;
    const int q0 = qb * 64;

    const float* Qb = Q + (size_t)bh * SEQ * DH;
    const short* Kh = Kb + (size_t)bh * SEQ * DH;
    const short* Vh = Vt + (size_t)bh * DH * SEQ;
    float* Ob = Out + (size_t)bh * SEQ * DH;

    // Q fragments (A-layout: m=l15, k=ks*32+l4*8+j), pre-scaled by 1/8
    bf16x8 qf[2];
    {
        const float* qp = Qb + (size_t)(q0 + wave * 16 + l15) * DH;
        #pragma unroll
        for (int ks = 0; ks < 2; ++ks) {
            short tmp[8];
            #pragma unroll
            for (int j = 0; j < 8; ++j) tmp[j] = f2b(qp[ks * 32 + l4 * 8 + j] * 0.125f);
            qf[ks] = *reinterpret_cast<bf16x8*>(tmp);
        }
    }

    f32x4 o_acc[4];
    #pragma unroll
    for (int dt = 0; dt < 4; ++dt) o_acc[dt] = f32x4{0.f, 0.f, 0.f, 0.f};
    float l_part[4] = {0.f, 0.f, 0.f, 0.f};

    // staging: K tile = 128 rows x 8 chunks = 1024 chunks; V tile = 64 rows x
    // 16 chunks = 1024 chunks. 256 threads x 4 slots each.
    const short* kg[4]; const short* vg[4]; short* kl[4]; short* vl[4];
    #pragma unroll
    for (int p = 0; p < 4; ++p) {
        int slot = p * 256 + tid;                // 0..1023
        int kr = slot >> 3, kc = slot & 7;       // K: row 0..127, chunk 0..7
        int kcg = kc ^ (kr & 7);
        kg[p] = Kh + (size_t)kr * DH + kcg * 8;
        kl[p] = &lds_k[(size_t)slot * 8];
        int vr = slot >> 4, vc = slot & 15;      // V: row 0..63, chunk 0..15
        int vcg = vc ^ (vr & 7);                 // XOR low 3 bits only
        vg[p] = Vh + (size_t)vr * SEQ + vcg * 8;
        vl[p] = &lds_v[(size_t)slot * 8];
    }
    const float* bp0 = Bias + (size_t)(q0 + wave * 16 + l4 * 4) * SEQ + l15;
    short* pw = &lds_p[wave * 16 * 64];
    const int swz = l15 & 7;                     // read-side XOR

    for (int kt = 0; kt < NTILE; ++kt) {
        const int k0 = kt * KV;
        __syncthreads();                          // prior tile reads done
        #pragma unroll
        for (int p = 0; p < 4; ++p) {
            gl_lds16(kg[p] + (size_t)k0 * DH, kl[p]);
            gl_lds16(vg[p] + k0, vl[p]);
        }

        // bias for half 0 (loads hidden under the staging drain)
        f32x4 sacc[4];
        {
            const float* bp = bp0 + k0;
            #pragma unroll
            for (int nt = 0; nt < 4; ++nt)
                #pragma unroll
                for (int r = 0; r < 4; ++r)
                    sacc[nt][r] = bp[(size_t)r * SEQ + nt * 16];
        }

        __syncthreads();                          // staging complete

        #pragma unroll
        for (int hh = 0; hh < 2; ++hh) {
            if (hh) {
                const float* bp = bp0 + k0 + 64;
                #pragma unroll
                for (int nt = 0; nt < 4; ++nt)
                    #pragma unroll
                    for (int r = 0; r < 4; ++r)
                        sacc[nt][r] = bp[(size_t)r * SEQ + nt * 16];
            }

            // QK^T on this 64-kv half
            #pragma unroll
            for (int ks = 0; ks < 2; ++ks)
                #pragma unroll
                for (int nt = 0; nt < 4; ++nt) {
                    int cc = (ks * 4 + l4) ^ swz;
                    bf16x8 kf = *(const bf16x8*)
                        &lds_k[(hh * 64 + nt * 16 + l15) * DH + cc * 8];
                    sacc[nt] = __builtin_amdgcn_mfma_f32_16x16x32_bf16(
                        qf[ks], kf, sacc[nt], 0, 0, 0);
                }

            // max-free softmax; P -> per-wave LDS (swizzled); l partials.
            // pw reuse across halves is safe: same-wave DS ops are ordered,
            // so half-0's P reads complete before half-1's overwrites.
            #pragma unroll
            for (int r = 0; r < 4; ++r) {
                const int prow = l4 * 4 + r;
                const int rsw = prow & 7;
                #pragma unroll
                for (int nt = 0; nt < 4; ++nt) {
                    float pv = __builtin_amdgcn_exp2f(sacc[nt][r] * LOG2E);
                    l_part[r] += pv;
                    int pc = (nt * 2 + (l15 >> 3)) ^ rsw;
                    pw[prow * 64 + pc * 8 + (l15 & 7)] = f2b(pv);
                }
            }

            // O += P @ V (V physical chunk = hh*8 + (logical^swz); bit 3 is
            // the half bit, untouched by the low-3-bit swizzle)
            #pragma unroll
            for (int ks = 0; ks < 2; ++ks) {
                int cc = (ks * 4 + l4) ^ swz;
                bf16x8 pf = *(const bf16x8*)&pw[l15 * 64 + cc * 8];
                #pragma unroll
                for (int dt = 0; dt < 4; ++dt) {
                    bf16x8 vf = *(const bf16x8*)
                        &lds_v[(dt * 16 + l15) * KV + (hh * 8 + cc) * 8];
                    o_acc[dt] = __builtin_amdgcn_mfma_f32_16x16x32_bf16(
                        pf, vf, o_acc[dt], 0, 0, 0);
                }
            }
        }
    }

    // l reduction across the 16-lane row groups
    #pragma unroll
    for (int r = 0; r < 4; ++r) {
        float s = l_part[r];
        #pragma unroll
        for (int m = 1; m < 16; m <<= 1) s += __shfl_xor(s, m, 64);
        l_part[r] = s;
    }

    #pragma unroll
    for (int r = 0; r < 4; ++r) {
        float inv = 1.0f / l_part[r];
        float* op = Ob + (size_t)(q0 + wave * 16 + l4 * 4 + r) * DH + l15;
        #pragma unroll
        for (int dt = 0; dt < 4; ++dt) op[dt * 16] = o_acc[dt][r] * inv;
    }
}

extern "C" void kernel_launch(void* const* d_in, const int* in_sizes, int n_in,
                              void* d_out, int out_size, void* d_ws, size_t ws_size,
                              hipStream_t stream) {
    const float* Q    = (const float*)d_in[0];
    const float* K    = (const float*)d_in[1];
    const float* V    = (const float*)d_in[2];
    const float* Bias = (const float*)d_in[3];
    float* O          = (float*)d_out;

    short* Kb = (short*)d_ws;                    // 8 MB
    short* Vt = Kb + (size_t)BHN * SEQ * DH;     // 8 MB

    prep_kv<<<dim3(BHN * 32), dim3(256), 0, stream>>>(K, V, Kb, Vt);
    mha_main<<<dim3(BHN * 32), dim3(256), 0, stream>>>(Q, Bias, Kb, Vt, O);
}

// Round 6
// 169.137 us; speedup vs baseline: 1.0736x; 1.0175x over previous
//
#include <hip/hip_runtime.h>
#include <hip/hip_bf16.h>

// Fused MHA fwd: out = softmax(scale*Q@K^T + bias) @ V
// B=2 H=16 S=2048 D=64, fp32 in/out, bf16 MFMA.
// R3 (84.5us, best): XOR-swizzled LDS, 16x16 MFMA, 4x16q waves, P via LDS.
// R4-R7: dbuf / in-reg-P variants all regressed.
// R8: KVBLK=128 + XCD swizzle regressed: swizzle destroyed BIAS L2 locality
//   (FETCH 86->175MB: default round-robin keeps only 4 bias slices = 2MB per
//   XCD L2; swizzle put all 32 there). Merged [64][128] V layout also brought
//   back 4.19M conflicts. Both poisons identified; KVBLK never isolated.
// R9: isolate KVBLK=128. R3 body bit-identical (same [64][64] tile layouts,
//   same read address math -> proven-zero conflicts), but TWO tiles staged per
//   barrier pair into lds_k[2][..]/lds_v[2][..]; halves computed back-to-back
//   with no barrier between. Barrier pairs 32->16, 8 outstanding gl_lds.
//   Both halves' bias preloaded to regs under the staging drain. No swizzle.

#define SEQ 2048
#define DH  64
#define BHN 32
#define NTILE (SEQ / 128)
#define LOG2E 1.44269504088896f

typedef __attribute__((ext_vector_type(8))) short bf16x8;
typedef __attribute__((ext_vector_type(4))) float f32x4;
typedef __attribute__((ext_vector_type(8))) short short8v;

__device__ inline short f2b(float x) {
    union { float f; unsigned u; } v; v.f = x;
    unsigned r = v.u + 0x7fff + ((v.u >> 16) & 1);
    return (short)(r >> 16);
}

__device__ inline void gl_lds16(const void* g, void* l) {
    __builtin_amdgcn_global_load_lds(
        (const __attribute__((address_space(1))) void*)g,
        (__attribute__((address_space(3))) void*)l, 16, 0, 0);
}

// ---- fused prep: K fp32->bf16 (same layout) + V fp32->bf16 transposed ----
__global__ __launch_bounds__(256)
void prep_kv(const float* __restrict__ K, const float* __restrict__ V,
             short* __restrict__ Kb, short* __restrict__ Vt) {
    __shared__ short t[64 * 72];
    const int tid = threadIdx.x;
    const int bh = blockIdx.x >> 5, st = blockIdx.x & 31, s0 = st * 64;

    {
        const float* Kp = K + ((size_t)bh * SEQ + s0) * DH;
        short* Ko = Kb + ((size_t)bh * SEQ + s0) * DH;
        #pragma unroll
        for (int i = 0; i < 2; ++i) {
            size_t o = (size_t)(tid + i * 256) * 8;
            f32x4 a = *(const f32x4*)(Kp + o);
            f32x4 b = *(const f32x4*)(Kp + o + 4);
            short8v s;
            #pragma unroll
            for (int j = 0; j < 4; ++j) { s[j] = f2b(a[j]); s[4 + j] = f2b(b[j]); }
            *(short8v*)(Ko + o) = s;
        }
    }

    const float* Vb = V + (size_t)bh * SEQ * DH + (size_t)s0 * DH;
    #pragma unroll
    for (int i = 0; i < 4; ++i) {
        int c = tid + i * 256, s = c >> 4, c4 = c & 15;
        f32x4 v = *(const f32x4*)(Vb + s * DH + c4 * 4);
        #pragma unroll
        for (int j = 0; j < 4; ++j) t[s * 72 + c4 * 4 + j] = f2b(v[j]);
    }
    __syncthreads();
    const int d = tid >> 2, part = tid & 3;
    short8v lo, hi;
    #pragma unroll
    for (int j = 0; j < 8; ++j) {
        lo[j] = t[(part * 16 + j) * 72 + d];
        hi[j] = t[(part * 16 + 8 + j) * 72 + d];
    }
    short* outp = Vt + (size_t)bh * DH * SEQ + (size_t)d * SEQ + s0 + part * 16;
    *(short8v*)outp = lo;
    *(short8v*)(outp + 8) = hi;
}

// ---- main fused attention ----
// LDS layouts XOR-swizzled exactly as R3: logical (row, 8-short chunk c) at
// physical chunk (c ^ (row&7)); staging fetches global chunk c^(row&7) into
// physical chunk c; reads use index (c ^ (row&7)). Proven-zero conflicts.
__global__ __launch_bounds__(256, 4)
void mha_main(const float* __restrict__ Q, const float* __restrict__ Bias,
              const short* __restrict__ Kb, const short* __restrict__ Vt,
              float* __restrict__ Out)
{
    __shared__ short lds_k[2][64 * DH];   // two K half-tiles [n][d], swizzled
    __shared__ short lds_v[2][64 * DH];   // two Vt half-tiles [d][n], swizzled
    __shared__ short lds_p[4 * 16 * 64];  // per-wave P [m][n], swizzled

    const int tid = threadIdx.x, lane = tid & 63, wave = tid >> 6;
    const int l15 = lane & 15, l4 = lane >> 4;
    const int qb = blockIdx.x & 31, bh = blockIdx.x >> 5;
    const int q0 = qb * 64;

    const float* Qb = Q + (size_t)bh * SEQ * DH;
    const short* Kh = Kb + (size_t)bh * SEQ * DH;
    const short* Vh = Vt + (size_t)bh * DH * SEQ;
    float* Ob = Out + (size_t)bh * SEQ * DH;

    // Q fragments (A-layout: m=l15, k=ks*32+l4*8+j), pre-scaled by 1/8
    bf16x8 qf[2];
    {
        const float* qp = Qb + (size_t)(q0 + wave * 16 + l15) * DH;
        #pragma unroll
        for (int ks = 0; ks < 2; ++ks) {
            short tmp[8];
            #pragma unroll
            for (int j = 0; j < 8; ++j) tmp[j] = f2b(qp[ks * 32 + l4 * 8 + j] * 0.125f);
            qf[ks] = *reinterpret_cast<bf16x8*>(tmp);
        }
    }

    f32x4 o_acc[4];
    #pragma unroll
    for (int dt = 0; dt < 4; ++dt) o_acc[dt] = f32x4{0.f, 0.f, 0.f, 0.f};
    float l_part[4] = {0.f, 0.f, 0.f, 0.f};

    // staging (R3-identical mechanics): lane's LDS slot fixed; fetch the
    // swizzled global chunk so physical chunk c holds global chunk c^(row&7).
    const short* kg[2]; const short* vg[2]; short* kl[2]; short* vl[2];
    #pragma unroll
    for (int p = 0; p < 2; ++p) {
        int slot = p * 256 + wave * 64 + lane;   // 0..511
        int r_ = slot >> 3;                      // row 0..63
        int c_ = slot & 7;                       // physical 16B chunk
        int cg = c_ ^ (r_ & 7);                  // global chunk to fetch
        kg[p] = Kh + (size_t)r_ * DH + cg * 8;
        vg[p] = Vh + (size_t)r_ * SEQ + cg * 8;
        kl[p] = &lds_k[0][(size_t)slot * 8];
        vl[p] = &lds_v[0][(size_t)slot * 8];
    }
    const float* bp0 = Bias + (size_t)(q0 + wave * 16 + l4 * 4) * SEQ + l15;
    short* pw = &lds_p[wave * 16 * 64];
    const int swz = l15 & 7;                     // read-side XOR

    for (int kt = 0; kt < NTILE; ++kt) {
        const int k0 = kt * 128;
        __syncthreads();                          // prior tile-pair reads done

        // stage BOTH 64-kv halves (8 outstanding gl_lds)
        #pragma unroll
        for (int hh = 0; hh < 2; ++hh) {
            const size_t koff = (size_t)(k0 + hh * 64) * DH;
            const int voff = k0 + hh * 64;
            const int lo = hh * (64 * DH);
            gl_lds16(kg[0] + koff, kl[0] + lo);
            gl_lds16(kg[1] + koff, kl[1] + lo);
            gl_lds16(vg[0] + voff, vl[0] + lo);
            gl_lds16(vg[1] + voff, vl[1] + lo);
        }

        // both halves' bias -> registers (hidden under the staging drain)
        f32x4 sacc[4];
        float b1[4][4];
        {
            const float* bp = bp0 + k0;
            #pragma unroll
            for (int nt = 0; nt < 4; ++nt)
                #pragma unroll
                for (int r = 0; r < 4; ++r) {
                    sacc[nt][r]  = bp[(size_t)r * SEQ + nt * 16];
                    b1[nt][r]    = bp[(size_t)r * SEQ + nt * 16 + 64];
                }
        }

        __syncthreads();                          // staging complete

        #pragma unroll
        for (int hh = 0; hh < 2; ++hh) {
            if (hh) {
                #pragma unroll
                for (int nt = 0; nt < 4; ++nt)
                    #pragma unroll
                    for (int r = 0; r < 4; ++r)
                        sacc[nt][r] = b1[nt][r];
            }

            const short* lk = lds_k[hh];
            const short* lv = lds_v[hh];

            // QK^T on this 64-kv half (R3 body verbatim)
            #pragma unroll
            for (int ks = 0; ks < 2; ++ks)
                #pragma unroll
                for (int nt = 0; nt < 4; ++nt) {
                    int cc = (ks * 4 + l4) ^ swz;
                    bf16x8 kf = *(const bf16x8*)&lk[(nt * 16 + l15) * DH + cc * 8];
                    sacc[nt] = __builtin_amdgcn_mfma_f32_16x16x32_bf16(
                        qf[ks], kf, sacc[nt], 0, 0, 0);
                }

            // max-free softmax; P -> per-wave LDS (swizzled); l partials.
            // pw reuse across halves: same-wave DS ops execute in order, so
            // half-0's P reads retire before half-1's overwrites (same
            // guarantee R3 used across barrier-separated iterations).
            #pragma unroll
            for (int r = 0; r < 4; ++r) {
                const int prow = l4 * 4 + r;
                const int rsw = prow & 7;
                #pragma unroll
                for (int nt = 0; nt < 4; ++nt) {
                    float pv = __builtin_amdgcn_exp2f(sacc[nt][r] * LOG2E);
                    l_part[r] += pv;
                    int pc = (nt * 2 + (l15 >> 3)) ^ rsw;
                    pw[prow * 64 + pc * 8 + (l15 & 7)] = f2b(pv);
                }
            }

            // O += P @ V
            #pragma unroll
            for (int ks = 0; ks < 2; ++ks) {
                int cc = (ks * 4 + l4) ^ swz;
                bf16x8 pf = *(const bf16x8*)&pw[l15 * 64 + cc * 8];
                #pragma unroll
                for (int dt = 0; dt < 4; ++dt) {
                    bf16x8 vf = *(const bf16x8*)&lv[(dt * 16 + l15) * DH + cc * 8];
                    o_acc[dt] = __builtin_amdgcn_mfma_f32_16x16x32_bf16(
                        pf, vf, o_acc[dt], 0, 0, 0);
                }
            }
        }
    }

    // l reduction across the 16-lane row groups
    #pragma unroll
    for (int r = 0; r < 4; ++r) {
        float s = l_part[r];
        #pragma unroll
        for (int m = 1; m < 16; m <<= 1) s += __shfl_xor(s, m, 64);
        l_part[r] = s;
    }

    #pragma unroll
    for (int r = 0; r < 4; ++r) {
        float inv = 1.0f / l_part[r];
        float* op = Ob + (size_t)(q0 + wave * 16 + l4 * 4 + r) * DH + l15;
        #pragma unroll
        for (int dt = 0; dt < 4; ++dt) op[dt * 16] = o_acc[dt][r] * inv;
    }
}

extern "C" void kernel_launch(void* const* d_in, const int* in_sizes, int n_in,
                              void* d_out, int out_size, void* d_ws, size_t ws_size,
                              hipStream_t stream) {
    const float* Q    = (const float*)d_in[0];
    const float* K    = (const float*)d_in[1];
    const float* V    = (const float*)d_in[2];
    const float* Bias = (const float*)d_in[3];
    float* O          = (float*)d_out;

    short* Kb = (short*)d_ws;                    // 8 MB
    short* Vt = Kb + (size_t)BHN * SEQ * DH;     // 8 MB

    prep_kv<<<dim3(BHN * 32), dim3(256), 0, stream>>>(K, V, Kb, Vt);
    mha_main<<<dim3(BHN * 32), dim3(256), 0, stream>>>(Q, Bias, Kb, Vt, O);
}